// Round 1
// baseline (1357.679 us; speedup 1.0000x reference)
//
#include <hip/hip_runtime.h>

#define NLAGC 20
#define NTC   100
#define DTC   0.01f
#define MU1C  0.06f
#define MU2C  0.02f
#define RC    0.02f
#define SIGC  0.2f
#define BETAC 0.05f
#define ETAC  0.5f
#define EPSC  1e-6f
#define UPENC 100.0f
#define YDECC 0.99004983374916805f   /* exp(-0.01) */
#define FDISCC 0.95122942450071403f  /* exp(-0.05) */
#define GEOMC 0.0081465072f          /* (1-exp(-0.01))*exp(-0.2) */

#define SPB 16    // samples per block
#define TPB 512   // threads per block
#define K8N 17    // ceil(130/8) k-octets (rows 130..135 zero-padded)
#define ZW  136   // z row width in floats: [x, h(128), t, pad(6)]

__device__ __forceinline__ float sigm(float x){ return 1.0f/(1.0f+__expf(-x)); }
__device__ __forceinline__ float tanhfast(float x){
    float a = fabsf(x);
    float e = __expf(-2.0f*a);          // in (0,1], no overflow
    float t = (1.0f-e)/(1.0f+e);
    return copysignf(t,x);
}
__device__ __forceinline__ unsigned short f2bf(float f){
    unsigned u = __float_as_uint(f);
    u += 0x7fffu + ((u>>16)&1u);        // round-to-nearest-even
    return (unsigned short)(u>>16);
}
__device__ __forceinline__ void unp8(uint4 u, float* w){
    w[0]=__uint_as_float(u.x<<16); w[1]=__uint_as_float(u.x&0xffff0000u);
    w[2]=__uint_as_float(u.y<<16); w[3]=__uint_as_float(u.y&0xffff0000u);
    w[4]=__uint_as_float(u.z<<16); w[5]=__uint_as_float(u.z&0xffff0000u);
    w[6]=__uint_as_float(u.w<<16); w[7]=__uint_as_float(u.w&0xffff0000u);
}

// GEMM for one LSTM step: each thread accumulates 4 gates x 4 samples over k=0..135.
#define GEMM_STEP(acc) do{ \
    _Pragma("unroll") for(int g_=0;g_<4;++g_){ _Pragma("unroll") for(int s_=0;s_<4;++s_) acc[g_][s_]=0.f; } \
    _Pragma("unroll 2") \
    for (int k8=0;k8<K8N;++k8){ \
        const uint4* wb = Wl4 + ((k8<<2)<<7) + j; \
        uint4 u0=wb[0], u1=wb[128], u2=wb[256], u3=wb[384]; \
        float w0[8],w1[8],w2[8],w3[8]; \
        unp8(u0,w0);unp8(u1,w1);unp8(u2,w2);unp8(u3,w3); \
        _Pragma("unroll") \
        for (int s_=0;s_<4;++s_){ \
            const float4* zp = (const float4*)&zl[row+s_][k8<<3]; \
            float4 za = zp[0], zbv = zp[1]; \
            float zv[8]={za.x,za.y,za.z,za.w,zbv.x,zbv.y,zbv.z,zbv.w}; \
            _Pragma("unroll") \
            for(int kk=0;kk<8;++kk){ \
                acc[0][s_]=fmaf(w0[kk],zv[kk],acc[0][s_]); \
                acc[1][s_]=fmaf(w1[kk],zv[kk],acc[1][s_]); \
                acc[2][s_]=fmaf(w2[kk],zv[kk],acc[2][s_]); \
                acc[3][s_]=fmaf(w3[kk],zv[kk],acc[3][s_]); \
            } \
        } \
    } \
}while(0)

__global__ __launch_bounds__(TPB, 2) void polstm(
    const float* __restrict__ dw,  const float* __restrict__ xin,
    const float* __restrict__ Wf,  const float* __restrict__ bfp,
    const float* __restrict__ Wi,  const float* __restrict__ bip,
    const float* __restrict__ Wo,  const float* __restrict__ bop,
    const float* __restrict__ Wc,  const float* __restrict__ bcp,
    const float* __restrict__ Wpi, const float* __restrict__ bpi,
    float* __restrict__ out)
{
    __shared__ uint4 Wl4[K8N*4*128];               // 139,264 B : bf16 weights [k8][gate][j][8k]
    __shared__ __align__(16) float zl[SPB][ZW];    // 8,704 B   : z = [x, h, t, pad]
    __shared__ float red[8][4][2];                 // per-wave pi partials

    const int tid  = threadIdx.x;
    const int j    = tid & 127;      // hidden unit
    const int sq   = tid >> 7;       // sample quad 0..3
    const int row  = sq << 2;        // first local sample
    const int wave = tid >> 6;
    const int lane = tid & 63;
    const int base = blockIdx.x * SPB;

    // ---- stage weights into LDS as bf16 (coalesced global reads) ----
    unsigned short* Wl = (unsigned short*)Wl4;
    for (int e = tid; e < K8N*4*8*128; e += TPB){
        int jj  = e & 127;
        int rem = e >> 7;
        int kk  = rem & 7;
        int g   = (rem >> 3) & 3;
        int k8  = rem >> 5;
        int k   = k8*8 + kk;
        float v = 0.0f;
        if (k < 130){
            const float* ws = (g==0)?Wf:((g==1)?Wi:((g==2)?Wo:Wc));
            v = ws[k*128 + jj];
        }
        Wl[((((k8<<2)+g)<<7) | jj)*8 + kk] = f2bf(v);
    }

    // ---- per-thread constants ----
    float bfr = bfp[j], bir = bip[j], bor = bop[j], bcr = bcp[j];
    float wp0 = Wpi[2*j], wp1 = Wpi[2*j+1];

    // ---- per-sample SDE state (threads tid<16 own sample s=tid) ----
    float x_s=0.f, y_s=0.f, rew_s=0.f, bp0=0.f, bp1=0.f;
    const int gs = base + tid;
    if (tid < SPB){
        x_s = xin[gs*21 + 20];
        float ysum = 0.f;
        #pragma unroll
        for (int i=0;i<NLAGC;++i)
            ysum += __expf(-DTC*(float)(NLAGC-i)) * xin[gs*21 + 1 + i];
        y_s = ysum*DTC + GEOMC*xin[gs*21];
        bp0 = bpi[0]; bp1 = bpi[1];
    }

    // ---- h0/C0 init, z buffer init ----
    float Creg[4];
    #pragma unroll
    for (int s=0;s<4;++s){
        int r = row+s;
        float h0 = (j==0) ? xin[(base+r)*21] : 0.f;
        Creg[s] = h0;
        zl[r][1+j] = h0;
    }
    if (j < 6){
        #pragma unroll
        for (int s=0;s<4;++s) zl[row+s][130+j] = 0.f;     // zero the k-pad
    }
    if (j == 0){
        #pragma unroll
        for (int s=0;s<4;++s){
            zl[row+s][0]   = xin[(base+row+s)*21 + 1];    // init x col 1
            zl[row+s][129] = -(float)NLAGC*DTC;           // t = -0.2
        }
    }

    // ---- init phase: 20 LSTM steps over lagged history ----
    #pragma unroll 1
    for (int m=0; m<NLAGC; ++m){
        __syncthreads();                 // z (and on m=0, weights) ready
        float acc[4][4];
        GEMM_STEP(acc);
        __syncthreads();                 // all reads of z done
        #pragma unroll
        for (int s=0;s<4;++s){
            float fg=acc[0][s]+bfr, ig=acc[1][s]+bir, og=acc[2][s]+bor, cg=acc[3][s]+bcr;
            Creg[s] = Creg[s]*sigm(fg) + tanhfast(cg)*sigm(ig);
            zl[row+s][1+j] = sigm(og)*tanhfast(Creg[s]);
        }
        if (j==0){
            #pragma unroll
            for (int s=0;s<4;++s){
                if (m < NLAGC-1) zl[row+s][0] = xin[(base+row+s)*21 + 2 + m]; // next lag col
                zl[row+s][129] = (float)(m+1-NLAGC)*DTC;                      // next t (0 on last)
            }
        }
    }
    // after init: z[s][0] holds x_init[:,20] == starting x; t-slot == 0.

    // ---- main phase: 100 steps with pi / SDE / reward ----
    #pragma unroll 1
    for (int t=0; t<NTC; ++t){
        __syncthreads();                 // z ready
        float acc[4][4];
        GEMM_STEP(acc);
        __syncthreads();                 // reads done
        float c0[4], c1[4];
        #pragma unroll
        for (int s=0;s<4;++s){
            float fg=acc[0][s]+bfr, ig=acc[1][s]+bir, og=acc[2][s]+bor, cg=acc[3][s]+bcr;
            Creg[s] = Creg[s]*sigm(fg) + tanhfast(cg)*sigm(ig);
            float h = sigm(og)*tanhfast(Creg[s]);
            zl[row+s][1+j] = h;
            c0[s] = h*wp0; c1[s] = h*wp1;
        }
        // reduce pi over 64 lanes (j-halves); combine the 2 waves per sq via LDS
        #pragma unroll
        for (int off=1; off<64; off<<=1){
            #pragma unroll
            for (int s=0;s<4;++s){
                c0[s] += __shfl_xor(c0[s], off, 64);
                c1[s] += __shfl_xor(c1[s], off, 64);
            }
        }
        if (lane==0){
            #pragma unroll
            for (int s=0;s<4;++s){ red[wave][s][0]=c0[s]; red[wave][s][1]=c1[s]; }
        }
        __syncthreads();                 // h + partials visible
        if (tid < SPB){
            int q = tid>>2, sl = tid&3;
            float p0 = red[2*q][sl][0] + red[2*q+1][sl][0] + bp0;
            float p1 = red[2*q][sl][1] + red[2*q+1][sl][1] + bp1;
            p0 = 2.0f*sigm(p0);
            p1 = 2.0f*sigm(p1);
            float tdt = (float)t*DTC;
            float ir = __logf(fmaxf(p0*x_s,0.f)+EPSC)*__expf(-BETAC*tdt) - fmaxf(-x_s,0.f)*UPENC;
            rew_s += ir*DTC;
            float dxv = ((MU1C-RC)*p1 - p0 + RC)*x_s + MU2C*y_s;
            x_s = x_s + dxv*DTC + SIGC*x_s*p1*dw[gs*NTC + t];
            y_s = y_s*YDECC + x_s*DTC;
            zl[tid][0]   = x_s;
            zl[tid][129] = (float)(t+1)*DTC;
        }
    }

    if (tid < SPB){
        rew_s += __logf(fmaxf(x_s + ETAC*y_s, 0.f)+EPSC)/BETAC*FDISCC - fmaxf(-x_s,0.f)*UPENC;
        out[gs] = -rew_s;
    }
}

extern "C" void kernel_launch(void* const* d_in, const int* in_sizes, int n_in,
                              void* d_out, int out_size, void* d_ws, size_t ws_size,
                              hipStream_t stream){
    const float* dw  = (const float*)d_in[0];
    const float* xin = (const float*)d_in[1];
    const float* Wf  = (const float*)d_in[2];
    const float* bf  = (const float*)d_in[3];
    const float* Wi  = (const float*)d_in[4];
    const float* bi  = (const float*)d_in[5];
    const float* Wo  = (const float*)d_in[6];
    const float* bo  = (const float*)d_in[7];
    const float* Wc  = (const float*)d_in[8];
    const float* bc  = (const float*)d_in[9];
    const float* Wpi = (const float*)d_in[10];
    const float* bpi = (const float*)d_in[11];
    float* out = (float*)d_out;
    int nblk = (out_size + SPB - 1) / SPB;   // 4096/16 = 256
    polstm<<<dim3(nblk), dim3(TPB), 0, stream>>>(dw, xin, Wf, bf, Wi, bi, Wo, bo, Wc, bc, Wpi, bpi, out);
}

// Round 2
// 266.448 us; speedup vs baseline: 5.0955x; 5.0955x over previous
//
#include <hip/hip_runtime.h>

#define NLAGC 20
#define NTC   100
#define DTC   0.01f
#define MU1C  0.06f
#define MU2C  0.02f
#define RC    0.02f
#define SIGC  0.2f
#define BETAC 0.05f
#define ETAC  0.5f
#define EPSC  1e-6f
#define UPENC 100.0f
#define YDECC 0.99004983374916805f   /* exp(-0.01) */
#define FDISCC 0.95122942450071403f  /* exp(-0.05) */
#define GEOMC 0.0081465072f          /* (1-exp(-0.01))*exp(-0.2) */

#define SPB 16    // samples per block (= MFMA M)
#define TPB 512   // 8 waves
#define NKT 5     // K tiles of 32 (K padded 130 -> 160)
#define ZSTR 168  // z row stride in bf16 elems (130 used, 160 read, 168 pad for banks)

typedef __attribute__((ext_vector_type(8))) short short8v;  // 8 bf16 = 4 VGPR
typedef __attribute__((ext_vector_type(4))) float f32x4;

__device__ __forceinline__ float sigm(float x){ return 1.0f/(1.0f+__expf(-x)); }
__device__ __forceinline__ float tanhfast(float x){
    float a=fabsf(x); float e=__expf(-2.0f*a);
    return copysignf((1.0f-e)/(1.0f+e), x);
}
__device__ __forceinline__ unsigned short f2bf(float f){
    unsigned u=__float_as_uint(f);
    u += 0x7fffu + ((u>>16)&1u);       // RNE
    return (unsigned short)(u>>16);
}

// one LSTM gate-GEMM + nonlinearity; writes new h (bf16) into zw
#define STEP_CORE() \
    short8v av[NKT]; \
    _Pragma("unroll") \
    for (int kt=0;kt<NKT;++kt) \
        av[kt] = *(const short8v*)&zr[col*ZSTR + kt*32 + kg*8]; \
    f32x4 a0={bg0,bg0,bg0,bg0}, a1={bg1,bg1,bg1,bg1}; \
    f32x4 a2={bg2,bg2,bg2,bg2}, a3={bg3,bg3,bg3,bg3}; \
    _Pragma("unroll") \
    for (int kt=0;kt<NKT;++kt){ \
        a0 = __builtin_amdgcn_mfma_f32_16x16x32_bf16(av[kt], bw[0][kt], a0,0,0,0); \
        a1 = __builtin_amdgcn_mfma_f32_16x16x32_bf16(av[kt], bw[1][kt], a1,0,0,0); \
        a2 = __builtin_amdgcn_mfma_f32_16x16x32_bf16(av[kt], bw[2][kt], a2,0,0,0); \
        a3 = __builtin_amdgcn_mfma_f32_16x16x32_bf16(av[kt], bw[3][kt], a3,0,0,0); \
    }

__global__ __launch_bounds__(TPB,2) void polstm(
    const float* __restrict__ dw,  const float* __restrict__ xin,
    const float* __restrict__ Wf,  const float* __restrict__ bfp,
    const float* __restrict__ Wi,  const float* __restrict__ bip,
    const float* __restrict__ Wo,  const float* __restrict__ bop,
    const float* __restrict__ Wc,  const float* __restrict__ bcp,
    const float* __restrict__ Wpi, const float* __restrict__ bpi,
    float* __restrict__ out)
{
    __shared__ unsigned short zbuf[2][SPB*ZSTR];   // 10,752 B double-buffered z (bf16)
    __shared__ float red[8][SPB][2];               // 1,024 B pi partials

    const int tid  = threadIdx.x;
    const int w    = tid>>6;        // wave 0..7 -> unit cols w*16..w*16+15
    const int lane = tid&63;
    const int col  = lane&15;       // B col within tile; also A row (sample)
    const int kg   = lane>>4;       // k subgroup 0..3
    const int j    = w*16+col;      // hidden unit owned by this lane
    const int base = blockIdx.x*SPB;
    const int gs   = base + tid;

    for (int e=tid; e<2*SPB*ZSTR; e+=TPB) ((unsigned short*)zbuf)[e]=0;

    // ---- stage all weights into per-lane register B-fragments (once) ----
    // B-frag layout (16x16x32): lane holds B[k=kt*32+kg*8+i][n=col], i=0..7
    short8v bw[4][NKT];
    #pragma unroll
    for (int g=0; g<4; ++g){
        const float* Wp = (g==0)?Wf:(g==1)?Wi:(g==2)?Wo:Wc;
        #pragma unroll
        for (int kt=0; kt<NKT; ++kt){
            short8v f;
            #pragma unroll
            for (int i=0;i<8;++i){
                int k = kt*32 + kg*8 + i;
                float v = (k<130)? Wp[k*128+j] : 0.0f;
                f[i] = (short)f2bf(v);
            }
            bw[g][kt]=f;
        }
    }
    const float bg0=bfp[j], bg1=bip[j], bg2=bop[j], bg3=bcp[j];
    const float wp0=Wpi[2*j], wp1=Wpi[2*j+1];

    // C state: lane holds C[sample=kg*4+r][unit=j]
    float C[4];
    #pragma unroll
    for (int r=0;r<4;++r)
        C[r] = (j==0)? xin[(base+kg*4+r)*21] : 0.0f;

    // SDE state (threads 0..15 own sample tid)
    float x_s=0.f,y_s=0.f,rew=0.f,bp0=0.f,bp1=0.f;
    if (tid<SPB){
        x_s = xin[gs*21+20];
        float ys=0.f;
        #pragma unroll
        for (int i=0;i<NLAGC;++i) ys += __expf(-DTC*(float)(NLAGC-i))*xin[gs*21+1+i];
        y_s = ys*DTC + GEOMC*xin[gs*21];
        bp0=bpi[0]; bp1=bpi[1];
    }

    __syncthreads();                     // zeroing done
    if (tid<SPB){                        // prologue: z for first init step
        zbuf[0][tid*ZSTR+0]   = f2bf(xin[gs*21+1]);   // first lag col
        zbuf[0][tid*ZSTR+1]   = f2bf(xin[gs*21+0]);   // h0[0]
        zbuf[0][tid*ZSTR+129] = f2bf(-(float)NLAGC*DTC);
    }

    unsigned short* zr = zbuf[0];
    unsigned short* zw = zbuf[1];

    // ---- init phase: 20 steps, 1 barrier each ----
    #pragma unroll 1
    for (int m=0; m<NLAGC; ++m){
        __syncthreads();                 // zr ready
        STEP_CORE();
        #pragma unroll
        for (int r=0;r<4;++r){
            float sf=sigm(a0[r]), si=sigm(a1[r]), so=sigm(a2[r]);
            C[r] = C[r]*sf + tanhfast(a3[r])*si;
            float h = so*tanhfast(C[r]);
            zw[(kg*4+r)*ZSTR + 1 + j] = f2bf(h);
        }
        if (tid<SPB){
            int idx = m+2; if (idx>20) idx=20;        // lag col for next step
            zw[tid*ZSTR+0]   = f2bf(xin[gs*21+idx]);
            zw[tid*ZSTR+129] = f2bf((float)(m+1-NLAGC)*DTC);
        }
        unsigned short* t_=zr; zr=zw; zw=t_;
    }

    // ---- main phase: 100 steps, 2 barriers each ----
    #pragma unroll 1
    for (int t=0;t<NTC;++t){
        __syncthreads();                 // zr ready
        STEP_CORE();
        float c0[4],c1[4];
        #pragma unroll
        for (int r=0;r<4;++r){
            float sf=sigm(a0[r]), si=sigm(a1[r]), so=sigm(a2[r]);
            C[r] = C[r]*sf + tanhfast(a3[r])*si;
            float h = so*tanhfast(C[r]);
            zw[(kg*4+r)*ZSTR + 1 + j] = f2bf(h);
            c0[r]=h*wp0; c1[r]=h*wp1;
        }
        #pragma unroll
        for (int off=1;off<16;off<<=1){  // reduce over the 16 unit-cols in wave
            #pragma unroll
            for (int r=0;r<4;++r){
                c0[r]+=__shfl_xor(c0[r],off,64);
                c1[r]+=__shfl_xor(c1[r],off,64);
            }
        }
        if (col==0){
            #pragma unroll
            for (int r=0;r<4;++r){ red[w][kg*4+r][0]=c0[r]; red[w][kg*4+r][1]=c1[r]; }
        }
        __syncthreads();                 // partials + h visible
        if (tid<SPB){
            float p0=bp0,p1=bp1;
            #pragma unroll
            for (int ww=0;ww<8;++ww){ p0+=red[ww][tid][0]; p1+=red[ww][tid][1]; }
            p0=2.0f*sigm(p0); p1=2.0f*sigm(p1);
            float tdt=(float)t*DTC;
            float ir=__logf(fmaxf(p0*x_s,0.0f)+EPSC)*__expf(-BETAC*tdt)-fmaxf(-x_s,0.0f)*UPENC;
            rew += ir*DTC;
            float dxv=((MU1C-RC)*p1-p0+RC)*x_s+MU2C*y_s;
            x_s = x_s + dxv*DTC + SIGC*x_s*p1*dw[gs*NTC+t];
            y_s = y_s*YDECC + x_s*DTC;
            zw[tid*ZSTR+0]  =f2bf(x_s);
            zw[tid*ZSTR+129]=f2bf((float)(t+1)*DTC);
        }
        unsigned short* t_=zr; zr=zw; zw=t_;
    }

    if (tid<SPB){
        rew += __logf(fmaxf(x_s+ETAC*y_s,0.0f)+EPSC)/BETAC*FDISCC - fmaxf(-x_s,0.0f)*UPENC;
        out[gs]=-rew;
    }
}

extern "C" void kernel_launch(void* const* d_in, const int* in_sizes, int n_in,
                              void* d_out, int out_size, void* d_ws, size_t ws_size,
                              hipStream_t stream){
    const float* dw  = (const float*)d_in[0];
    const float* xin = (const float*)d_in[1];
    const float* Wf  = (const float*)d_in[2];
    const float* bf  = (const float*)d_in[3];
    const float* Wi  = (const float*)d_in[4];
    const float* bi  = (const float*)d_in[5];
    const float* Wo  = (const float*)d_in[6];
    const float* bo  = (const float*)d_in[7];
    const float* Wc  = (const float*)d_in[8];
    const float* bc  = (const float*)d_in[9];
    const float* Wpi = (const float*)d_in[10];
    const float* bpi = (const float*)d_in[11];
    float* out = (float*)d_out;
    int nblk = (out_size + SPB - 1) / SPB;   // 256
    polstm<<<dim3(nblk), dim3(TPB), 0, stream>>>(dw, xin, Wf, bf, Wi, bi, Wo, bo, Wc, bc, Wpi, bpi, out);
}

// Round 3
// 194.987 us; speedup vs baseline: 6.9629x; 1.3665x over previous
//
#include <hip/hip_runtime.h>

#define NLAGC 20
#define NTC   100
#define DTC   0.01f
#define MU1C  0.06f
#define MU2C  0.02f
#define RC    0.02f
#define SIGC  0.2f
#define BETAC 0.05f
#define ETAC  0.5f
#define EPSC  1e-6f
#define UPENC 100.0f
#define YDECC 0.99004983374916805f   /* exp(-0.01) */
#define FDISCC 0.95122942450071403f  /* exp(-0.05) */
#define GEOMC 0.0081465072f          /* (1-exp(-0.01))/1*exp(-0.2) */
#define DFACTC 0.99950012497916927f  /* exp(-beta*dt) */

#define SPB 16    // samples per block (= MFMA M)
#define TPB 512   // 8 waves
#define NKT 4     // K tiles of 32 over h (K=128; x,t folded into acc init)
#define ZSTR 136  // z row stride in bf16 (128 h + 8 pad -> 2-way-free banks)

typedef __attribute__((ext_vector_type(8))) short short8v;
typedef __attribute__((ext_vector_type(4))) float f32x4;

__device__ __forceinline__ float sigm(float x){ return __builtin_amdgcn_rcpf(1.0f+__expf(-x)); }
__device__ __forceinline__ float tanhr(float x){ return 1.0f-2.0f*__builtin_amdgcn_rcpf(1.0f+__expf(2.0f*x)); }
__device__ __forceinline__ unsigned short f2bf(float f){
    unsigned u=__float_as_uint(f);
    u += 0x7fffu + ((u>>16)&1u);       // RNE
    return (unsigned short)(u>>16);
}

__global__ __launch_bounds__(TPB,2) void polstm(
    const float* __restrict__ dw,  const float* __restrict__ xin,
    const float* __restrict__ Wf,  const float* __restrict__ bfp,
    const float* __restrict__ Wi,  const float* __restrict__ bip,
    const float* __restrict__ Wo,  const float* __restrict__ bop,
    const float* __restrict__ Wc,  const float* __restrict__ bcp,
    const float* __restrict__ Wpi, const float* __restrict__ bpi,
    float* __restrict__ out)
{
    __shared__ __align__(16) unsigned short zbuf[2][SPB*ZSTR];  // 8704 B h double-buffer
    __shared__ float dwl[SPB*NTC];                              // 6400 B
    __shared__ float xl[SPB*21];                                // 1344 B

    const int tid=threadIdx.x, w=tid>>6, lane=tid&63, col=lane&15, kg=lane>>4;
    const int j=w*16+col;                // hidden unit owned by this lane
    const int base=blockIdx.x*SPB;

    for(int e=tid;e<2*SPB*ZSTR;e+=TPB) ((unsigned short*)zbuf)[e]=0;
    for(int e=tid;e<SPB*NTC;e+=TPB) dwl[e]=dw[base*NTC+e];
    for(int e=tid;e<SPB*21;e+=TPB)  xl[e]=xin[base*21+e];

    // ---- weights -> register B-fragments (once) ----
    // B-frag (16x16x32): lane holds B[k=kt*32+kg*8+i][n=col]
    short8v bw[4][NKT], bpif[NKT];
    float wx[4], wt[4], bg[4];
    #pragma unroll
    for(int g=0;g<4;++g){
        const float* Wp=(g==0)?Wf:(g==1)?Wi:(g==2)?Wo:Wc;
        const float* bv=(g==0)?bfp:(g==1)?bip:(g==2)?bop:bcp;
        wx[g]=Wp[j]; wt[g]=Wp[129*128+j]; bg[g]=bv[j];
        #pragma unroll
        for(int kt=0;kt<NKT;++kt){
            short8v f;
            #pragma unroll
            for(int i=0;i<8;++i) f[i]=(short)f2bf(Wp[(1+kt*32+kg*8+i)*128+j]);
            bw[g][kt]=f;
        }
    }
    #pragma unroll
    for(int kt=0;kt<NKT;++kt){
        short8v f;
        #pragma unroll
        for(int i=0;i<8;++i){
            int k=kt*32+kg*8+i;
            int idx=k*2+((col<2)?col:0);          // keep reads in-bounds
            float v=Wpi[idx];
            f[i]=(short)((col<2)?f2bf(v):(unsigned short)0);
        }
        bpif[kt]=f;
    }
    const float bp0=bpi[0], bp1=bpi[1];

    __syncthreads();                     // LDS staged (zeros + dwl + xl)

    // ---- per-sample state: lane (col==0) group owns samples kg*4+r ----
    float C[4], xs[4], ys[4], rew[4];
    #pragma unroll
    for(int r=0;r<4;++r){
        int s=kg*4+r;
        float x0=xl[s*21];
        C[r]=(j==0)?x0:0.0f;
        xs[r]=xl[s*21+20];
        float acc=0.f;
        #pragma unroll
        for(int i=0;i<NLAGC;++i) acc+=__expf(-DTC*(float)(NLAGC-i))*xl[s*21+1+i];
        ys[r]=acc*DTC+GEOMC*x0;
        rew[r]=0.f;
    }
    if(j==0){                            // h0 = [x0, 0...0]
        #pragma unroll
        for(int r=0;r<4;++r) zbuf[0][(kg*4+r)*ZSTR+0]=f2bf(xl[(kg*4+r)*21]);
    }

    unsigned short* zr=zbuf[0];
    unsigned short* zw=zbuf[1];

    // ---- init phase: 20 steps, 1 barrier each, no pi/SDE ----
    #pragma unroll 1
    for(int m=0;m<NLAGC;++m){
        __syncthreads();
        short8v av[NKT];
        {   const unsigned short* zp=zr+col*ZSTR+kg*8;
            #pragma unroll
            for(int kt=0;kt<NKT;++kt) av[kt]=*(const short8v*)(zp+kt*32);
        }
        float tval=(float)(m-NLAGC)*DTC;
        float xr0=xl[(kg*4+0)*21+1+m], xr1=xl[(kg*4+1)*21+1+m];
        float xr2=xl[(kg*4+2)*21+1+m], xr3=xl[(kg*4+3)*21+1+m];
        float b0=fmaf(wt[0],tval,bg[0]), b1=fmaf(wt[1],tval,bg[1]);
        float b2=fmaf(wt[2],tval,bg[2]), b3=fmaf(wt[3],tval,bg[3]);
        f32x4 a0={fmaf(wx[0],xr0,b0),fmaf(wx[0],xr1,b0),fmaf(wx[0],xr2,b0),fmaf(wx[0],xr3,b0)};
        f32x4 a1={fmaf(wx[1],xr0,b1),fmaf(wx[1],xr1,b1),fmaf(wx[1],xr2,b1),fmaf(wx[1],xr3,b1)};
        f32x4 a2={fmaf(wx[2],xr0,b2),fmaf(wx[2],xr1,b2),fmaf(wx[2],xr2,b2),fmaf(wx[2],xr3,b2)};
        f32x4 a3={fmaf(wx[3],xr0,b3),fmaf(wx[3],xr1,b3),fmaf(wx[3],xr2,b3),fmaf(wx[3],xr3,b3)};
        #pragma unroll
        for(int kt=0;kt<NKT;++kt){
            a0=__builtin_amdgcn_mfma_f32_16x16x32_bf16(av[kt],bw[0][kt],a0,0,0,0);
            a1=__builtin_amdgcn_mfma_f32_16x16x32_bf16(av[kt],bw[1][kt],a1,0,0,0);
            a2=__builtin_amdgcn_mfma_f32_16x16x32_bf16(av[kt],bw[2][kt],a2,0,0,0);
            a3=__builtin_amdgcn_mfma_f32_16x16x32_bf16(av[kt],bw[3][kt],a3,0,0,0);
        }
        #pragma unroll
        for(int r=0;r<4;++r){
            C[r]=C[r]*sigm(a0[r])+tanhr(a3[r])*sigm(a1[r]);
            float h=sigm(a2[r])*tanhr(C[r]);
            zw[(kg*4+r)*ZSTR+j]=f2bf(h);
        }
        unsigned short* tp=zr; zr=zw; zw=tp;
    }

    // ---- main phase: t=0..99 compute; SDE(t-1) done at iter t; iter 100 = epilogue SDE ----
    float disc=1.0f;
    #pragma unroll 1
    for(int t=0;t<=NTC;++t){
        __syncthreads();
        short8v av[NKT];
        {   const unsigned short* zp=zr+col*ZSTR+kg*8;
            #pragma unroll
            for(int kt=0;kt<NKT;++kt) av[kt]=*(const short8v*)(zp+kt*32);
        }
        // pi_{t-1} = h_{t-1} @ Wpi via MFMA (av holds h_{t-1}); cols 0/1 of D
        f32x4 a4={0.f,0.f,0.f,0.f};
        #pragma unroll
        for(int kt=0;kt<NKT;++kt)
            a4=__builtin_amdgcn_mfma_f32_16x16x32_bf16(av[kt],bpif[kt],a4,0,0,0);
        float q0=__shfl_xor(a4[0],1,64), q1=__shfl_xor(a4[1],1,64);
        float q2=__shfl_xor(a4[2],1,64), q3=__shfl_xor(a4[3],1,64);
        if(t>0){
            if(col==0){
                float qq0=q0,qq1=q1,qq2=q2,qq3=q3;
                float pr0[4]={a4[0],a4[1],a4[2],a4[3]};
                float pr1[4]={qq0,qq1,qq2,qq3};
                #pragma unroll
                for(int r=0;r<4;++r){
                    int s=kg*4+r;
                    float p0=2.0f*sigm(pr0[r]+bp0);
                    float p1=2.0f*sigm(pr1[r]+bp1);
                    float xo=xs[r];
                    float ir=__logf(fmaxf(p0*xo,0.f)+EPSC)*disc-fmaxf(-xo,0.f)*UPENC;
                    rew[r]+=ir*DTC;
                    float dxv=((MU1C-RC)*p1-p0+RC)*xo+MU2C*ys[r];
                    float xn=xo+dxv*DTC+SIGC*xo*p1*dwl[s*NTC+(t-1)];
                    xs[r]=xn;
                    ys[r]=ys[r]*YDECC+xn*DTC;
                }
                disc*=DFACTC;
            }
        }
        if(t==NTC) break;
        // broadcast x to all lanes of the kg row-group
        float xr0=__shfl(xs[0],lane&48,64), xr1=__shfl(xs[1],lane&48,64);
        float xr2=__shfl(xs[2],lane&48,64), xr3=__shfl(xs[3],lane&48,64);
        float tval=(float)t*DTC;
        float b0=fmaf(wt[0],tval,bg[0]), b1=fmaf(wt[1],tval,bg[1]);
        float b2=fmaf(wt[2],tval,bg[2]), b3=fmaf(wt[3],tval,bg[3]);
        f32x4 a0={fmaf(wx[0],xr0,b0),fmaf(wx[0],xr1,b0),fmaf(wx[0],xr2,b0),fmaf(wx[0],xr3,b0)};
        f32x4 a1={fmaf(wx[1],xr0,b1),fmaf(wx[1],xr1,b1),fmaf(wx[1],xr2,b1),fmaf(wx[1],xr3,b1)};
        f32x4 a2={fmaf(wx[2],xr0,b2),fmaf(wx[2],xr1,b2),fmaf(wx[2],xr2,b2),fmaf(wx[2],xr3,b2)};
        f32x4 a3={fmaf(wx[3],xr0,b3),fmaf(wx[3],xr1,b3),fmaf(wx[3],xr2,b3),fmaf(wx[3],xr3,b3)};
        #pragma unroll
        for(int kt=0;kt<NKT;++kt){
            a0=__builtin_amdgcn_mfma_f32_16x16x32_bf16(av[kt],bw[0][kt],a0,0,0,0);
            a1=__builtin_amdgcn_mfma_f32_16x16x32_bf16(av[kt],bw[1][kt],a1,0,0,0);
            a2=__builtin_amdgcn_mfma_f32_16x16x32_bf16(av[kt],bw[2][kt],a2,0,0,0);
            a3=__builtin_amdgcn_mfma_f32_16x16x32_bf16(av[kt],bw[3][kt],a3,0,0,0);
        }
        #pragma unroll
        for(int r=0;r<4;++r){
            C[r]=C[r]*sigm(a0[r])+tanhr(a3[r])*sigm(a1[r]);
            float h=sigm(a2[r])*tanhr(C[r]);
            zw[(kg*4+r)*ZSTR+j]=f2bf(h);
        }
        unsigned short* tp=zr; zr=zw; zw=tp;
    }

    // ---- final utility + output ----
    if(col==0){
        #pragma unroll
        for(int r=0;r<4;++r)
            rew[r]+=__logf(fmaxf(xs[r]+ETAC*ys[r],0.f)+EPSC)*(FDISCC/BETAC)-fmaxf(-xs[r],0.f)*UPENC;
        if(w==0){
            #pragma unroll
            for(int r=0;r<4;++r) out[base+kg*4+r]=-rew[r];
        }
    }
}

extern "C" void kernel_launch(void* const* d_in, const int* in_sizes, int n_in,
                              void* d_out, int out_size, void* d_ws, size_t ws_size,
                              hipStream_t stream){
    const float* dw  = (const float*)d_in[0];
    const float* xin = (const float*)d_in[1];
    const float* Wf  = (const float*)d_in[2];
    const float* bf  = (const float*)d_in[3];
    const float* Wi  = (const float*)d_in[4];
    const float* bi  = (const float*)d_in[5];
    const float* Wo  = (const float*)d_in[6];
    const float* bo  = (const float*)d_in[7];
    const float* Wc  = (const float*)d_in[8];
    const float* bc  = (const float*)d_in[9];
    const float* Wpi = (const float*)d_in[10];
    const float* bpi = (const float*)d_in[11];
    float* out = (float*)d_out;
    int nblk = (out_size + SPB - 1) / SPB;   // 256
    polstm<<<dim3(nblk), dim3(TPB), 0, stream>>>(dw, xin, Wf, bf, Wi, bi, Wo, bo, Wc, bc, Wpi, bpi, out);
}

// Round 4
// 150.148 us; speedup vs baseline: 9.0423x; 1.2986x over previous
//
#include <hip/hip_runtime.h>

#define NLAGC 20
#define NTC   100
#define DTC   0.01f
#define MU1C  0.06f
#define MU2C  0.02f
#define RC    0.02f
#define SIGC  0.2f
#define BETAC 0.05f
#define ETAC  0.5f
#define EPSC  1e-6f
#define UPENC 100.0f
#define YDECC 0.99004983374916805f   /* exp(-0.01) */
#define FDISCC 0.95122942450071403f  /* exp(-0.05) */
#define GEOMC 0.0081465072f          /* (1-exp(-0.01))*exp(-0.2) */
#define DFACTC 0.99950012497916927f  /* exp(-beta*dt) */

#define SPB 16    // samples per block (= MFMA M)
#define TPB 512   // 8 waves
#define NKT 4     // K tiles of 32 over h (K=128; x,t,b folded into acc init/post-fmac)
#define ZSTR 136  // z row stride in bf16 (128 h + 8 pad)

typedef __attribute__((ext_vector_type(8))) short short8v;
typedef __attribute__((ext_vector_type(4))) float f32x4;

__device__ __forceinline__ float sigm(float x){ return __builtin_amdgcn_rcpf(1.0f+__expf(-x)); }
__device__ __forceinline__ float tanhr(float x){ return 1.0f-2.0f*__builtin_amdgcn_rcpf(1.0f+__expf(2.0f*x)); }
__device__ __forceinline__ unsigned short f2bf(float f){            // RNE (one-time staging)
    unsigned u=__float_as_uint(f);
    u += 0x7fffu + ((u>>16)&1u);
    return (unsigned short)(u>>16);
}
__device__ __forceinline__ unsigned short f2bf_rna(float f){        // 2-inst RN-away (hot path)
    return (unsigned short)((__float_as_uint(f)+0x8000u)>>16);
}

__global__ __launch_bounds__(TPB,2) void polstm(
    const float* __restrict__ dw,  const float* __restrict__ xin,
    const float* __restrict__ Wf,  const float* __restrict__ bfp,
    const float* __restrict__ Wi,  const float* __restrict__ bip,
    const float* __restrict__ Wo,  const float* __restrict__ bop,
    const float* __restrict__ Wc,  const float* __restrict__ bcp,
    const float* __restrict__ Wpi, const float* __restrict__ bpi,
    float* __restrict__ out)
{
    __shared__ __align__(16) unsigned short zbuf[2][SPB*ZSTR];  // 8704 B h double-buffer
    __shared__ float dwl[SPB*NTC];                              // 6400 B
    __shared__ float xl[SPB*21];                                // 1344 B
    __shared__ __align__(16) float pibuf[2][SPB];               // 128 B pi exchange

    const int tid=threadIdx.x, w=tid>>6, lane=tid&63, col=lane&15, kg=lane>>4;
    const int j=w*16+col;                // hidden unit owned by this lane
    const int base=blockIdx.x*SPB;

    for(int e=tid;e<2*SPB*ZSTR;e+=TPB) ((unsigned short*)zbuf)[e]=0;
    for(int e=tid;e<SPB*NTC;e+=TPB) dwl[e]=dw[base*NTC+e];
    for(int e=tid;e<SPB*21;e+=TPB)  xl[e]=xin[base*21+e];

    // ---- weights -> register B-fragments (once) ----
    short8v bw[4][NKT], bpif[NKT];
    float wx[4], wt[4], bg[4];
    #pragma unroll
    for(int g=0;g<4;++g){
        const float* Wp=(g==0)?Wf:(g==1)?Wi:(g==2)?Wo:Wc;
        const float* bv=(g==0)?bfp:(g==1)?bip:(g==2)?bop:bcp;
        wx[g]=Wp[j]; wt[g]=Wp[129*128+j]; bg[g]=bv[j];
        #pragma unroll
        for(int kt=0;kt<NKT;++kt){
            short8v f;
            #pragma unroll
            for(int i=0;i<8;++i) f[i]=(short)f2bf(Wp[(1+kt*32+kg*8+i)*128+j]);
            bw[g][kt]=f;
        }
    }
    #pragma unroll
    for(int kt=0;kt<NKT;++kt){
        short8v f;
        #pragma unroll
        for(int i=0;i<8;++i){
            int k=kt*32+kg*8+i;
            int idx=k*2+((col<2)?col:0);
            float v=Wpi[idx];
            f[i]=(short)((col<2)?f2bf(v):(unsigned short)0);
        }
        bpif[kt]=f;
    }
    const float bp0=bpi[0], bp1=bpi[1];

    __syncthreads();                     // LDS staged

    // ---- per-lane state ----
    float C[4];
    #pragma unroll
    for(int r=0;r<4;++r) C[r]=(j==0)?xl[(kg*4+r)*21]:0.0f;

    float xs=0.f, ys=0.f, rew=0.f;       // lane l<16 owns sample l
    if(lane<SPB){
        float x0=xl[lane*21];
        xs=xl[lane*21+20];
        float acc=0.f;
        #pragma unroll
        for(int i=0;i<NLAGC;++i) acc+=__expf(-DTC*(float)(NLAGC-i))*xl[lane*21+1+i];
        ys=acc*DTC+GEOMC*x0;
    }
    if(j==0){                            // h0 = [x0, 0...0]
        #pragma unroll
        for(int r=0;r<4;++r) zbuf[0][(kg*4+r)*ZSTR+0]=f2bf(xl[(kg*4+r)*21]);
    }

    unsigned short* zr=zbuf[0];
    unsigned short* zw=zbuf[1];

    // ---- init phase: 20 steps ----
    #pragma unroll 1
    for(int m=0;m<NLAGC;++m){
        __syncthreads();
        short8v av[NKT];
        {   const unsigned short* zp=zr+col*ZSTR+kg*8;
            #pragma unroll
            for(int kt=0;kt<NKT;++kt) av[kt]=*(const short8v*)(zp+kt*32);
        }
        float tval=(float)(m-NLAGC)*DTC;
        float xr0=xl[(kg*4+0)*21+1+m], xr1=xl[(kg*4+1)*21+1+m];
        float xr2=xl[(kg*4+2)*21+1+m], xr3=xl[(kg*4+3)*21+1+m];
        float b0=fmaf(wt[0],tval,bg[0]), b1=fmaf(wt[1],tval,bg[1]);
        float b2=fmaf(wt[2],tval,bg[2]), b3=fmaf(wt[3],tval,bg[3]);
        f32x4 a0={fmaf(wx[0],xr0,b0),fmaf(wx[0],xr1,b0),fmaf(wx[0],xr2,b0),fmaf(wx[0],xr3,b0)};
        f32x4 a1={fmaf(wx[1],xr0,b1),fmaf(wx[1],xr1,b1),fmaf(wx[1],xr2,b1),fmaf(wx[1],xr3,b1)};
        f32x4 a2={fmaf(wx[2],xr0,b2),fmaf(wx[2],xr1,b2),fmaf(wx[2],xr2,b2),fmaf(wx[2],xr3,b2)};
        f32x4 a3={fmaf(wx[3],xr0,b3),fmaf(wx[3],xr1,b3),fmaf(wx[3],xr2,b3),fmaf(wx[3],xr3,b3)};
        #pragma unroll
        for(int kt=0;kt<NKT;++kt){
            a0=__builtin_amdgcn_mfma_f32_16x16x32_bf16(av[kt],bw[0][kt],a0,0,0,0);
            a1=__builtin_amdgcn_mfma_f32_16x16x32_bf16(av[kt],bw[1][kt],a1,0,0,0);
            a2=__builtin_amdgcn_mfma_f32_16x16x32_bf16(av[kt],bw[2][kt],a2,0,0,0);
            a3=__builtin_amdgcn_mfma_f32_16x16x32_bf16(av[kt],bw[3][kt],a3,0,0,0);
        }
        #pragma unroll
        for(int r=0;r<4;++r){
            C[r]=C[r]*sigm(a0[r])+tanhr(a3[r])*sigm(a1[r]);
            float h=sigm(a2[r])*tanhr(C[r]);
            zw[(kg*4+r)*ZSTR+j]=f2bf_rna(h);
        }
        unsigned short* tp=zr; zr=zw; zw=tp;
    }

    // ---- main phase ----
    float disc=1.0f;
    #pragma unroll 1
    for(int t=0;t<=NTC;++t){
        __syncthreads();
        short8v av[NKT];
        {   const unsigned short* zp=zr+col*ZSTR+kg*8;
            #pragma unroll
            for(int kt=0;kt<NKT;++kt) av[kt]=*(const short8v*)(zp+kt*32);
        }
        // pi_{t-1} chain first (feeds SDE soonest)
        f32x4 a4={0.f,0.f,0.f,0.f};
        #pragma unroll
        for(int kt=0;kt<NKT;++kt)
            a4=__builtin_amdgcn_mfma_f32_16x16x32_bf16(av[kt],bpif[kt],a4,0,0,0);
        // gate MFMAs overlap pi/SDE: acc starts at b + wt*t; x-term fmac'd after
        float tval=(float)t*DTC;
        float tb0=fmaf(wt[0],tval,bg[0]), tb1=fmaf(wt[1],tval,bg[1]);
        float tb2=fmaf(wt[2],tval,bg[2]), tb3=fmaf(wt[3],tval,bg[3]);
        f32x4 a0={tb0,tb0,tb0,tb0}, a1={tb1,tb1,tb1,tb1};
        f32x4 a2={tb2,tb2,tb2,tb2}, a3={tb3,tb3,tb3,tb3};
        #pragma unroll
        for(int kt=0;kt<NKT;++kt){
            a0=__builtin_amdgcn_mfma_f32_16x16x32_bf16(av[kt],bw[0][kt],a0,0,0,0);
            a1=__builtin_amdgcn_mfma_f32_16x16x32_bf16(av[kt],bw[1][kt],a1,0,0,0);
            a2=__builtin_amdgcn_mfma_f32_16x16x32_bf16(av[kt],bw[2][kt],a2,0,0,0);
            a3=__builtin_amdgcn_mfma_f32_16x16x32_bf16(av[kt],bw[3][kt],a3,0,0,0);
        }
        // distribute pi rows to lanes 0..15 (same-wave LDS write->read; all waves
        // write identical values so cross-wave races are benign)
        if(col<2) *(f32x4*)&pibuf[col][kg*4] = a4;
        if(t>0 && lane<SPB){
            float p0=2.0f*sigm(pibuf[0][lane]+bp0);
            float p1=2.0f*sigm(pibuf[1][lane]+bp1);
            float ir=__logf(fmaxf(p0*xs,0.f)+EPSC)*disc-fmaxf(-xs,0.f)*UPENC;
            rew+=ir*DTC;
            float dxv=((MU1C-RC)*p1-p0+RC)*xs+MU2C*ys;
            xs=xs+dxv*DTC+SIGC*xs*p1*dwl[lane*NTC+(t-1)];
            ys=ys*YDECC+xs*DTC;
        }
        if(t>0) disc*=DFACTC;
        if(t==NTC) break;
        // broadcast x_t to the kg row-group and fold into gate accs
        int srcb=(lane>>4)<<2;
        float xr0=__shfl(xs,srcb,64),   xr1=__shfl(xs,srcb+1,64);
        float xr2=__shfl(xs,srcb+2,64), xr3=__shfl(xs,srcb+3,64);
        a0[0]=fmaf(wx[0],xr0,a0[0]); a0[1]=fmaf(wx[0],xr1,a0[1]); a0[2]=fmaf(wx[0],xr2,a0[2]); a0[3]=fmaf(wx[0],xr3,a0[3]);
        a1[0]=fmaf(wx[1],xr0,a1[0]); a1[1]=fmaf(wx[1],xr1,a1[1]); a1[2]=fmaf(wx[1],xr2,a1[2]); a1[3]=fmaf(wx[1],xr3,a1[3]);
        a2[0]=fmaf(wx[2],xr0,a2[0]); a2[1]=fmaf(wx[2],xr1,a2[1]); a2[2]=fmaf(wx[2],xr2,a2[2]); a2[3]=fmaf(wx[2],xr3,a2[3]);
        a3[0]=fmaf(wx[3],xr0,a3[0]); a3[1]=fmaf(wx[3],xr1,a3[1]); a3[2]=fmaf(wx[3],xr2,a3[2]); a3[3]=fmaf(wx[3],xr3,a3[3]);
        #pragma unroll
        for(int r=0;r<4;++r){
            C[r]=C[r]*sigm(a0[r])+tanhr(a3[r])*sigm(a1[r]);
            float h=sigm(a2[r])*tanhr(C[r]);
            zw[(kg*4+r)*ZSTR+j]=f2bf_rna(h);
        }
        unsigned short* tp=zr; zr=zw; zw=tp;
    }

    // ---- final utility + output ----
    if(lane<SPB){
        rew+=__logf(fmaxf(xs+ETAC*ys,0.f)+EPSC)*(FDISCC/BETAC)-fmaxf(-xs,0.f)*UPENC;
        if(w==0) out[base+lane]=-rew;
    }
}

extern "C" void kernel_launch(void* const* d_in, const int* in_sizes, int n_in,
                              void* d_out, int out_size, void* d_ws, size_t ws_size,
                              hipStream_t stream){
    const float* dw  = (const float*)d_in[0];
    const float* xin = (const float*)d_in[1];
    const float* Wf  = (const float*)d_in[2];
    const float* bf  = (const float*)d_in[3];
    const float* Wi  = (const float*)d_in[4];
    const float* bi  = (const float*)d_in[5];
    const float* Wo  = (const float*)d_in[6];
    const float* bo  = (const float*)d_in[7];
    const float* Wc  = (const float*)d_in[8];
    const float* bc  = (const float*)d_in[9];
    const float* Wpi = (const float*)d_in[10];
    const float* bpi = (const float*)d_in[11];
    float* out = (float*)d_out;
    int nblk = (out_size + SPB - 1) / SPB;   // 256
    polstm<<<dim3(nblk), dim3(TPB), 0, stream>>>(dw, xin, Wf, bf, Wi, bi, Wo, bo, Wc, bc, Wpi, bpi, out);
}